// Round 5
// baseline (58.467 us; speedup 1.0000x reference)
//
#include <hip/hip_runtime.h>
#include <math.h>

#define NB 8192
#define NK 64
#define NGLOBAL 16384
#define INV_T 0.5f                   // 1/TEMPERATURE
#define C_EXP2 0.72134752044448170f  // log2(e)/2 : exp2(x*C) == exp(x/2)

#if defined(__has_builtin)
#if __has_builtin(__builtin_amdgcn_exp2f)
#define EXP2(x) __builtin_amdgcn_exp2f(x)
#endif
#endif
#ifndef EXP2
#define EXP2(x) exp2f(x)
#endif

// ---------------------------------------------------------------------------
// Workspace layout:
//   [0, 64KB)     g2l table (int[NGLOBAL]) — never initialized; lookups are
//                 validated with bidx[col]==gi so stale/poison entries can
//                 never pass.
//   [64KB, 96KB)  row partials (float[NB])
// ---------------------------------------------------------------------------

// Kernel 1: scatter g2l[batch_indices[i]] = i.
__global__ __launch_bounds__(256) void scatter_kernel(
    const int* __restrict__ bidx, int* __restrict__ g2l, int b) {
    int i = blockIdx.x * blockDim.x + threadIdx.x;
    if (i < b) {
        int g = bidx[i];
        if ((unsigned)g < (unsigned)NGLOBAL) g2l[g] = i;  // OOB dropped
    }
}

// Kernel 2: one block (256 thr) per TWO rows.
//  - 16 float4 stream loads in flight per thread (MLP), exp2 consume
//  - waves 0/1 each own one row's teacher phase (validated g2l lookup,
//    last-wins dedup via wave-local __shfl, diagonal override, KL terms)
__global__ __launch_bounds__(256) void row_loss_kernel(
    const float* __restrict__ S,        // [NB, NB]
    const float* __restrict__ tscore,   // [NB, NK]
    const int* __restrict__ tindex,     // [NB, NK]
    const int* __restrict__ g2l,        // [NGLOBAL]
    const int* __restrict__ bidx,       // [NB]
    float* __restrict__ row_out)        // [NB]
{
    const int r0 = blockIdx.x * 2;
    const int t  = threadIdx.x;
    const float4* rp0 = reinterpret_cast<const float4*>(S + (size_t)r0 * NB);
    const float4* rp1 = reinterpret_cast<const float4*>(S + (size_t)(r0 + 1) * NB);

    // ---- issue all 16 stream loads (64 VGPRs payload, MLP=16) ----
    float4 v0[8], v1[8];
#pragma unroll
    for (int i = 0; i < 8; ++i) v0[i] = rp0[i * 256 + t];
#pragma unroll
    for (int i = 0; i < 8; ++i) v1[i] = rp1[i * 256 + t];

    // ---- teacher prefetch (waves 0,1): chain hides under exp phase ----
    int col = -1; bool valid = false; float sc = 0.f, gl = 0.f, gd = 0.f;
    const int myrow = r0 + (t >> 6);                 // wave w -> row r0+w
    if (t < 2 * NK) {
        const int lane = t & 63;
        const float* __restrict__ Srow = S + (size_t)myrow * NB;
        int gi = tindex[(size_t)myrow * NK + lane];
        gi = min(max(gi, 0), NGLOBAL - 1);           // clip like reference
        col = g2l[gi];
        valid = ((unsigned)col < (unsigned)NB) && (bidx[col] == gi)
                && (col != myrow);                   // diag forced later
        sc = tscore[(size_t)myrow * NK + lane];
        gl = Srow[valid ? col : myrow];              // gathered student logit
        gd = Srow[myrow];                            // diagonal logit
    }

    // Loads cannot sink past a may-write asm: all must be in flight here.
    asm volatile("" ::: "memory");

    // ---- per-row sums of exp(s/T) = exp2(s * log2e/2) ----
    float a0 = 0.f, a1 = 0.f, a2 = 0.f, a3 = 0.f;
    float b0 = 0.f, b1 = 0.f, b2 = 0.f, b3 = 0.f;
#pragma unroll
    for (int i = 0; i < 8; ++i) {
        a0 += EXP2(v0[i].x * C_EXP2);
        a1 += EXP2(v0[i].y * C_EXP2);
        a2 += EXP2(v0[i].z * C_EXP2);
        a3 += EXP2(v0[i].w * C_EXP2);
    }
#pragma unroll
    for (int i = 0; i < 8; ++i) {
        b0 += EXP2(v1[i].x * C_EXP2);
        b1 += EXP2(v1[i].y * C_EXP2);
        b2 += EXP2(v1[i].z * C_EXP2);
        b3 += EXP2(v1[i].w * C_EXP2);
    }
    float sa = (a0 + a1) + (a2 + a3);
    float sb = (b0 + b1) + (b2 + b3);
#pragma unroll
    for (int off = 32; off >= 1; off >>= 1) {
        sa += __shfl_xor(sa, off);
        sb += __shfl_xor(sb, off);
    }
    __shared__ float sredA[4], sredB[4];
    if ((t & 63) == 0) { sredA[t >> 6] = sa; sredB[t >> 6] = sb; }
    __syncthreads();
    const float lseA = __logf((sredA[0] + sredA[1]) + (sredA[2] + sredA[3]));
    const float lseB = __logf((sredB[0] + sredB[1]) + (sredB[2] + sredB[3]));

    if (t >= 2 * NK) return;          // waves 2,3 done; waves 0,1 continue
    const float lse = (t < NK) ? lseA : lseB;
    const int lane = t & 63;

    // ---- last-write-wins dedup (wave-local __shfl, uniform loop) ----
    int mycol = valid ? col : -1;
    bool live = valid;
#pragma unroll 1
    for (int k = 1; k < NK; ++k) {
        int ck = __shfl(mycol, k);
        if (valid && lane < k && ck == mycol) live = false;
    }

    float part = live ? sc : 0.f;     // sum of surviving scattered scores
#pragma unroll
    for (int off = 32; off >= 1; off >>= 1) part += __shfl_xor(part, off);
    const float row_sum = 1.0f + part;            // + diagonal 1.0

    float term = 0.f;
    if (live && sc > 0.f) {
        float tv = sc / row_sum;
        float logp = fmaf(gl, INV_T, -lse);
        term = tv * (__logf(tv) - logp);
    }
    if (lane == 0) {                  // diagonal target
        float td = 1.0f / row_sum;
        float logp = fmaf(gd, INV_T, -lse);
        term += td * (__logf(td) - logp);
    }
#pragma unroll
    for (int off = 32; off >= 1; off >>= 1) term += __shfl_xor(term, off);
    if (lane == 0) row_out[myrow] = term;
}

// Kernel 3: reduce 8192 row partials -> scalar (1024 thr, double accum).
__global__ __launch_bounds__(1024) void final_reduce_kernel(
    const float* __restrict__ row_out, float* __restrict__ out) {
    const int t = threadIdx.x;
    const float4* rp = reinterpret_cast<const float4*>(row_out);
    float4 w0 = rp[t], w1 = rp[1024 + t];
    asm volatile("" ::: "memory");
    double acc = (double)((w0.x + w0.y) + (w0.z + w0.w))
               + (double)((w1.x + w1.y) + (w1.z + w1.w));
#pragma unroll
    for (int off = 32; off >= 1; off >>= 1) acc += __shfl_xor(acc, off);
    __shared__ double sd[16];
    if ((t & 63) == 0) sd[t >> 6] = acc;
    __syncthreads();
    if (t == 0) {
        double total = 0.0;
#pragma unroll
        for (int i = 0; i < 16; ++i) total += sd[i];
        out[0] = (float)(total / (double)NB * 4.0);   // * T^2
    }
}

extern "C" void kernel_launch(void* const* d_in, const int* in_sizes, int n_in,
                              void* d_out, int out_size, void* d_ws, size_t ws_size,
                              hipStream_t stream) {
    const float* S      = (const float*)d_in[0];   // student_logits [B,B] f32
    const float* tscore = (const float*)d_in[1];   // teacher_scores [B,K] f32
    const int*   bidx   = (const int*)d_in[2];     // batch_indices [B] i32
    const int*   tindex = (const int*)d_in[3];     // teacher_indices [B,K] i32
    float* out = (float*)d_out;
    const int b = in_sizes[2];                     // = NB

    int*   g2l     = (int*)d_ws;
    float* row_out = (float*)((char*)d_ws + NGLOBAL * sizeof(int));

    scatter_kernel<<<(b + 255) / 256, 256, 0, stream>>>(bidx, g2l, b);
    row_loss_kernel<<<NB / 2, 256, 0, stream>>>(S, tscore, tindex, g2l, bidx, row_out);
    final_reduce_kernel<<<1, 1024, 0, stream>>>(row_out, out);
}